// Round 4
// baseline (2338.116 us; speedup 1.0000x reference)
//
#include <hip/hip_runtime.h>
#include <math.h>

// B=256, T=2048, D=64, U=128, 4U=512, COND=32
namespace {
constexpr int kB    = 256;
constexpr int kT    = 2048;
constexpr int kD    = 64;
constexpr int kU    = 128;
constexpr int kCOND = 32;
}

typedef _Float16 h2 __attribute__((ext_vector_type(2)));

__device__ __forceinline__ float sig_(float z) {
    return 1.0f / (1.0f + __expf(-z));
}
__device__ __forceinline__ float tanh_(float z) {
    float ez = __expf(-2.0f * fabsf(z));
    float t  = (1.0f - ez) / (1.0f + ez);
    return copysignf(t, z);
}
__device__ __forceinline__ float dot2_(h2 a, h2 b, float c) {
    return __builtin_amdgcn_fdot2(a, b, c, false);   // v_dot2_f32_f16
}
// DPP permute (pure VALU). 0xB1=quad_perm xor1, 0x4E=quad_perm xor2,
// 0x128=row_ror:8 == xor8 within a 16-lane row.
template <int CTRL>
__device__ __forceinline__ float dppmov_(float v) {
    return __int_as_float(
        __builtin_amdgcn_update_dpp(0, __float_as_int(v), CTRL, 0xF, 0xF, true));
}

union F4H { float4 f4; h2 h[4]; };

// One WG (1024 thr = 16 waves) per batch element, persistent over T steps.
// Thread = (colgroup j in [0,128), slice s in [0,8)). Columns {j+128i},
// i=0..3 = gate (i,f,c,o). Slice s: x[8s..8s+8) + h[16s..16s+16).
// s lives in lane bits {0,1,3}; split-K combine is a DPP reduce-scatter
// (14 instrs) leaving each lane exactly its publish value.
// Phase 2 overlaps the x-part dot2s for step t+1 (global->reg, f16 pack)
// with the gate nonlinearity chain on waves 0-1.
__global__ __launch_bounds__(1024, 4)
__attribute__((amdgpu_waves_per_eu(4, 4)))
void lstm_rs(const float* __restrict__ x,     // [B,T,D]
             const float* __restrict__ cond,  // [B,COND]
             const float* __restrict__ Wc,    // [COND,U]
             const float* __restrict__ bc,    // [U]
             const float* __restrict__ Wk,    // [D,4U]
             const float* __restrict__ Uk,    // [U,4U]
             const float* __restrict__ bias,  // [4U]
             float* __restrict__ out) {       // [B,U]
    const int b    = blockIdx.x;
    const int tid  = threadIdx.x;
    const int lane = tid & 63;
    const int wav  = tid >> 6;
    const int s    = (lane & 3) | ((lane >> 1) & 4);        // lane bits 0,1,3
    const int jl   = ((lane >> 2) & 1) | ((lane >> 3) & 6); // lane bits 2,4,5
    const int j    = wav * 8 + jl;                          // colgroup 0..127
    const bool s0 = (lane & 1) != 0;
    const bool s1 = (lane & 2) != 0;
    const bool s2 = (lane & 8) != 0;

    __shared__ __align__(16) _Float16 hsh[kU];   // h state, f16
    __shared__ __align__(16) float    g4[kU * 4]; // gate preacts, [u][i,f,c,o]

    // ---- f16 weights: 4 cols x (4 x-pairs + 8 h-pairs) = 48 h2 VGPRs ----
    h2 wx[4][4];
    h2 wh[4][8];
#pragma unroll
    for (int i = 0; i < 4; ++i) {
        const int c = j + kU * i;
#pragma unroll
        for (int kk = 0; kk < 4; ++kk) {
            const int d = s * 8 + 2 * kk;
            h2 w; w.x = (_Float16)Wk[d * 512 + c]; w.y = (_Float16)Wk[(d + 1) * 512 + c];
            wx[i][kk] = w;
        }
#pragma unroll
        for (int kk = 0; kk < 8; ++kk) {
            const int u = s * 16 + 2 * kk;
            h2 w; w.x = (_Float16)Uk[u * 512 + c]; w.y = (_Float16)Uk[(u + 1) * 512 + c];
            wh[i][kk] = w;
        }
    }

    // ---- per-state constants + initial state (threads 0..127) ----
    float c_reg = 0.0f, h_out = 0.0f;
    float bi = 0.0f, bf = 0.0f, bcg = 0.0f, bo = 0.0f;
    if (tid < kU) {
        bi  = bias[tid];
        bf  = bias[kU + tid];
        bcg = bias[2 * kU + tid];
        bo  = bias[3 * kU + tid];
        float a = bc[tid];
        const float* cr = cond + b * kCOND;
#pragma unroll
        for (int k = 0; k < kCOND; ++k) a = fmaf(cr[k], Wc[k * kU + tid], a);
        c_reg = a;
        h_out = a;
        hsh[tid] = (_Float16)a;
    }

    const float* xbase = x + (size_t)b * kT * kD + 8 * s;  // this thread's x slice
    const int    pubw  = 4 * j + 2 * (int)s2 + (int)s1;    // publish word (bank-clean)

    // ---- x-part partials for t=0 ----
    float px0, px1, px2, px3;
    {
        float4 xa = *(const float4*)(xbase);
        float4 xc = *(const float4*)(xbase + 4);
        h2 xh[4];
        xh[0].x = (_Float16)xa.x; xh[0].y = (_Float16)xa.y;
        xh[1].x = (_Float16)xa.z; xh[1].y = (_Float16)xa.w;
        xh[2].x = (_Float16)xc.x; xh[2].y = (_Float16)xc.y;
        xh[3].x = (_Float16)xc.z; xh[3].y = (_Float16)xc.w;
        px0 = px1 = px2 = px3 = 0.0f;
#pragma unroll
        for (int kk = 0; kk < 4; ++kk) {
            px0 = dot2_(xh[kk], wx[0][kk], px0);
            px1 = dot2_(xh[kk], wx[1][kk], px1);
            px2 = dot2_(xh[kk], wx[2][kk], px2);
            px3 = dot2_(xh[kk], wx[3][kk], px3);
        }
    }
    __syncthreads();

#pragma unroll 1
    for (int t = 0; t < kT; ++t) {
        // ---- P1: h-part dots + reduce-scatter + publish ----
        const float4* hp = (const float4*)hsh;
        F4H uh0, uh1;
        uh0.f4 = hp[2 * s];       // h[16s..16s+8)
        uh1.f4 = hp[2 * s + 1];   // h[16s+8..16s+16)

        float a0 = px0, a1 = px1, a2 = px2, a3 = px3;
#pragma unroll
        for (int kk = 0; kk < 4; ++kk) {
            a0 = dot2_(uh0.h[kk], wh[0][kk], a0);
            a1 = dot2_(uh0.h[kk], wh[1][kk], a1);
            a2 = dot2_(uh0.h[kk], wh[2][kk], a2);
            a3 = dot2_(uh0.h[kk], wh[3][kk], a3);
        }
#pragma unroll
        for (int kk = 0; kk < 4; ++kk) {
            a0 = dot2_(uh1.h[kk], wh[0][4 + kk], a0);
            a1 = dot2_(uh1.h[kk], wh[1][4 + kk], a1);
            a2 = dot2_(uh1.h[kk], wh[2][4 + kk], a2);
            a3 = dot2_(uh1.h[kk], wh[3][4 + kk], a3);
        }

        // reduce-scatter over the 8 s-lanes (bits 3,1,0): 14 VALU instrs.
        // Round A (xor8): s2=0 keeps {a0,a1}, s2=1 keeps {a2,a3}.
        float sAx = s2 ? a0 : a2;
        float sAy = s2 ? a1 : a3;
        float rAx = dppmov_<0x128>(sAx);
        float rAy = dppmov_<0x128>(sAy);
        float vA  = (s2 ? a2 : a0) + rAx;   // holds gate 2*s2
        float vB  = (s2 ? a3 : a1) + rAy;   // holds gate 2*s2+1
        // Round B (xor2): s1=0 keeps vA, s1=1 keeps vB.
        float sB = s1 ? vA : vB;
        float rB = dppmov_<0x4E>(sB);
        float vC = (s1 ? vB : vA) + rB;     // holds gate 2*s2+s1
        // Round C (xor1): final sum, duplicated on the s0 pair.
        float g  = vC + dppmov_<0xB1>(vC);

        if (!s0) g4[pubw] = g;              // 32 lanes, 32 distinct banks
        __syncthreads();

        // ---- P2: gates (waves 0-1) overlapped with x-dots for t+1 ----
        float4 gv;
        if (tid < kU) gv = ((const float4*)g4)[tid];   // one ds_read_b128

        const int tn = (t + 1 < kT) ? (t + 1) : t;
        const float* xn = xbase + (size_t)tn * kD;
        float4 xa = *(const float4*)(xn);
        float4 xc = *(const float4*)(xn + 4);
        h2 xh[4];
        xh[0].x = (_Float16)xa.x; xh[0].y = (_Float16)xa.y;
        xh[1].x = (_Float16)xa.z; xh[1].y = (_Float16)xa.w;
        xh[2].x = (_Float16)xc.x; xh[2].y = (_Float16)xc.y;
        xh[3].x = (_Float16)xc.z; xh[3].y = (_Float16)xc.w;
        px0 = px1 = px2 = px3 = 0.0f;
#pragma unroll
        for (int kk = 0; kk < 4; ++kk) {
            px0 = dot2_(xh[kk], wx[0][kk], px0);
            px1 = dot2_(xh[kk], wx[1][kk], px1);
            px2 = dot2_(xh[kk], wx[2][kk], px2);
            px3 = dot2_(xh[kk], wx[3][kk], px3);
        }

        if (tid < kU) {
            float iv = sig_(gv.x + bi);
            float fv = sig_(gv.y + bf);
            float cb = tanh_(gv.z + bcg);
            float ov = sig_(gv.w + bo);
            c_reg = fmaf(fv, c_reg, iv * cb);
            h_out = ov * tanh_(c_reg);
            hsh[tid] = (_Float16)h_out;
        }
        __syncthreads();
    }

    if (tid < kU) out[b * kU + tid] = h_out;
}

extern "C" void kernel_launch(void* const* d_in, const int* in_sizes, int n_in,
                              void* d_out, int out_size, void* d_ws, size_t ws_size,
                              hipStream_t stream) {
    const float* x    = (const float*)d_in[0];
    const float* cond = (const float*)d_in[1];
    const float* Wc   = (const float*)d_in[2];
    const float* bc   = (const float*)d_in[3];
    const float* Wk   = (const float*)d_in[4];
    const float* Uk   = (const float*)d_in[5];
    const float* b    = (const float*)d_in[6];
    float* out = (float*)d_out;

    lstm_rs<<<dim3(kB), dim3(1024), 0, stream>>>(x, cond, Wc, bc, Wk, Uk, b, out);
}